// Round 4
// baseline (8640.884 us; speedup 1.0000x reference)
//
#include <hip/hip_runtime.h>
#include <math.h>

namespace {

constexpr int Bsz = 8192;
constexpr int Fsz = 256;

typedef float  f32x4 __attribute__((ext_vector_type(4)));
typedef short  s16x8 __attribute__((ext_vector_type(8)));

// ---- compile-time Clifford algebra tables (Cl(3,0), CEGNN blade order) ----
struct Tables {
  int   jidx[64];
  float sgn[64];
  int   path[64];
  int   gr[8];
};

constexpr int cpopc(int v) { int c = 0; while (v) { c += v & 1; v >>= 1; } return c; }

constexpr Tables make_tables() {
  Tables t{};
  constexpr int MASKS[8] = {0, 1, 2, 4, 3, 5, 6, 7};
  int inv[8] = {};
  for (int i = 0; i < 8; ++i) inv[MASKS[i]] = i;
  int grade[8] = {};
  for (int i = 0; i < 8; ++i) { grade[i] = cpopc(MASKS[i]); t.gr[i] = grade[i]; }
  int pidx[4][4][4] = {};
  for (int a = 0; a < 4; ++a)
    for (int b = 0; b < 4; ++b)
      for (int c = 0; c < 4; ++c) pidx[a][b][c] = -1;
  int np = 0;
  for (int gi = 0; gi < 4; ++gi)
    for (int gj = 0; gj < 4; ++gj)
      for (int gk = 0; gk < 4; ++gk) {
        bool any = false;
        for (int i = 0; i < 8; ++i)
          for (int k = 0; k < 8; ++k)
            if (grade[i] == gi && grade[k] == gk && cpopc(MASKS[i] ^ MASKS[k]) == gj) any = true;
        if (any) pidx[gi][gj][gk] = np++;
      }
  for (int i = 0; i < 8; ++i)
    for (int k = 0; k < 8; ++k) {
      const int mi = MASKS[i], mk = MASKS[k];
      int s = 0, aa = mi >> 1;
      while (aa) { s += cpopc(aa & mk); aa >>= 1; }
      t.jidx[i * 8 + k] = inv[mi ^ mk];
      t.sgn[i * 8 + k]  = (s & 1) ? -1.0f : 1.0f;
      t.path[i * 8 + k] = pidx[grade[i]][cpopc(mi ^ mk)][grade[k]];
    }
  return t;
}

__device__ inline unsigned short f2bf(float f) {
  unsigned u = __builtin_bit_cast(unsigned, f);
  unsigned r = (u + 0x7FFFu + ((u >> 16) & 1u)) >> 16;
  return (unsigned short)r;
}

// ============================================================
// zflags: zero the probe flag region (first ints of d_out;
// final sgp_fused overwrites all of d_out afterwards)
// ============================================================
__global__ void zflags(int* flags) {
  if (threadIdx.x < 8) flags[threadIdx.x] = 0;
}

// ============================================================
// k1: x [8192][256][8] f32  ->  xt planes [8][8192][256] bf16
// ============================================================
__global__ __launch_bounds__(256) void xpose(const float* __restrict__ x,
                                             unsigned short* __restrict__ xt) {
  const int t  = threadIdx.x;
  const int b  = blockIdx.x * 32 + (t >> 3);
  const int m0 = blockIdx.y * 64 + (t & 7) * 8;

  float v[8][8];
  const float* src = x + ((size_t)b * Fsz + m0) * 8;
  #pragma unroll
  for (int mm = 0; mm < 8; ++mm) {
    float4 a = *(const float4*)(src + (size_t)mm * 8);
    float4 c = *(const float4*)(src + (size_t)mm * 8 + 4);
    v[mm][0] = a.x; v[mm][1] = a.y; v[mm][2] = a.z; v[mm][3] = a.w;
    v[mm][4] = c.x; v[mm][5] = c.y; v[mm][6] = c.z; v[mm][7] = c.w;
  }
  #pragma unroll
  for (int i = 0; i < 8; ++i) {
    unsigned short o[8];
    #pragma unroll
    for (int mm = 0; mm < 8; ++mm) o[mm] = f2bf(v[mm][i]);
    *(s16x8*)(xt + ((size_t)i * Bsz + b) * Fsz + m0) = *(const s16x8*)o;
  }
}

// ============================================================
// k1w: wl/wr [n][m][4] f32 -> wb [lr*4+g][n][m] bf16
// ============================================================
__global__ __launch_bounds__(256) void wpack(const float* __restrict__ wl,
                                             const float* __restrict__ wr,
                                             unsigned short* __restrict__ wb) {
  const int o  = blockIdx.x * 256 + threadIdx.x;
  const int m4 = o & 63;
  const int n  = (o >> 6) & 255;
  const int g  = (o >> 14) & 3;
  const int lr = (o >> 16) & 1;
  const float* w = lr ? wr : wl;
  const float* s = w + ((size_t)n * Fsz + m4 * 4) * 4 + g;
  unsigned short p[4];
  #pragma unroll
  for (int j = 0; j < 4; ++j) p[j] = f2bf(s[(size_t)j * 4]);
  *(uint2*)(wb + (((size_t)(lr * 4 + g) * Fsz + n) * Fsz) + m4 * 4) =
      *(const uint2*)p;
}

// ============================================================
// xcheck: spot-verify xt against independent recompute -> flags[3]
// ============================================================
__global__ __launch_bounds__(256) void xcheck(const float* __restrict__ x,
                                              const unsigned short* __restrict__ xt,
                                              int* __restrict__ flags) {
  const int gid = blockIdx.x * 256 + threadIdx.x;
  int bad = 0;
  for (int j = 0; j < 32; ++j) {
    unsigned e = ((unsigned)gid * 33u + (unsigned)j * 524309u) & 16777215u;
    int i = e >> 21;
    int b = (e >> 8) & 8191;
    int m = e & 255;
    unsigned short a = xt[e];
    unsigned short r = f2bf(x[((size_t)b * Fsz + m) * 8 + i]);
    if (a != r) bad++;
  }
  if (bad) atomicAdd(flags + 3, bad);
}

// ============================================================
// mfma_cmp: round-3 K-loop verbatim, then compare accumulators
// against fp32 references under competing C/D-layout hypotheses.
//   flags[0]: left acc wrong under (col=lane&15,row=quad*4+reg)
//   flags[1]: left acc wrong under transposed hypothesis
//   flags[2]: right acc wrong under standard hypothesis
// ============================================================
__global__ __launch_bounds__(256) void mfma_cmp(
    const unsigned short* __restrict__ xt,
    const unsigned short* __restrict__ wb,
    const float* __restrict__ x,
    const float* __restrict__ wl,
    const float* __restrict__ wr,
    int* __restrict__ flags)
{
  constexpr Tables T = make_tables();

  __shared__ __align__(16) char smem[32768];
  char* As = smem;
  char* Bs = smem + 16384;

  const int t    = threadIdx.x;
  const int wave = t >> 6;
  const int lane = t & 63;
  const int rlo  = lane & 15;
  const int quad = lane >> 4;
  const int wbh  = wave & 1;
  const int wnh  = wave >> 1;
  const int b0 = blockIdx.x * 32;
  const int n0 = blockIdx.y * 32;

  f32x4 acc[8][2];
  #pragma unroll
  for (int i = 0; i < 8; ++i)
    #pragma unroll
    for (int l = 0; l < 2; ++l)
      acc[i][l] = (f32x4){0.f, 0.f, 0.f, 0.f};

  for (int k0 = 0; k0 < Fsz; k0 += 32) {
    #pragma unroll
    for (int j = 0; j < 4; ++j) {
      const int o   = j * 4096 + t * 16;
      const int pi  = o >> 11;
      const int row = (o >> 6) & 31;
      const int kb  = o & 63;
      *(int4*)(As + o) = *(const int4*)((const char*)xt +
          (((size_t)pi * Bsz + b0 + row) * 512) + k0 * 2 + kb);
      *(int4*)(Bs + o) = *(const int4*)((const char*)wb +
          (((size_t)pi * Fsz + n0 + row) * 512) + k0 * 2 + kb);
    }
    __syncthreads();

    s16x8 bf[8];
    #pragma unroll
    for (int p = 0; p < 8; ++p)
      bf[p] = *(const s16x8*)(Bs + ((p * 32) + wnh * 16 + rlo) * 64 + quad * 16);

    #pragma unroll
    for (int i = 0; i < 8; ++i) {
      s16x8 af = *(const s16x8*)(As + i * 2048 + (wbh * 16 + rlo) * 64 + quad * 16);
      acc[i][0] = __builtin_amdgcn_mfma_f32_16x16x32_bf16(af, bf[T.gr[i]],
                                                          acc[i][0], 0, 0, 0);
      acc[i][1] = __builtin_amdgcn_mfma_f32_16x16x32_bf16(af, bf[4 + T.gr[i]],
                                                          acc[i][1], 0, 0, 0);
    }
    __syncthreads();
  }

  // ---- hypothesis checks (fp32 recompute; bf16 tol 0.125) ----
  int bad_c = 0, bad_t = 0, bad_r = 0;
  const int iset[4] = {0, 1, 4, 7};
  #pragma unroll
  for (int rr = 0; rr < 2; ++rr) {
    const int r  = rr * 2;
    const int bc = b0 + wbh * 16 + quad * 4 + r;   // standard-map b
    const int nc = n0 + wnh * 16 + rlo;            // standard-map n
    const int bt = b0 + wbh * 16 + rlo;            // transposed-map b
    const int nt = n0 + wnh * 16 + quad * 4 + r;   // transposed-map n
    #pragma unroll
    for (int s = 0; s < 4; ++s) {
      const int i = iset[s];
      const int g = T.gr[i];
      float refc = 0.f, reft = 0.f, refr = 0.f;
      for (int m = 0; m < Fsz; ++m) {
        const float xc = x[((size_t)bc * Fsz + m) * 8 + i];
        const float xtv = x[((size_t)bt * Fsz + m) * 8 + i];
        refc += xc  * wl[((size_t)nc * Fsz + m) * 4 + g];
        reft += xtv * wl[((size_t)nt * Fsz + m) * 4 + g];
        refr += xc  * wr[((size_t)nc * Fsz + m) * 4 + g];
      }
      if (fabsf(acc[i][0][r] - refc) > 0.125f) bad_c++;
      if (fabsf(acc[i][0][r] - reft) > 0.125f) bad_t++;
      if (fabsf(acc[i][1][r] - refr) > 0.125f) bad_r++;
    }
  }
  if (bad_c) atomicAdd(flags + 0, bad_c);
  if (bad_t) atomicAdd(flags + 1, bad_t);
  if (bad_r) atomicAdd(flags + 2, bad_r);
}

// ============================================================
// spin_probe: encode flag bits in duration.
//   dur ~= 50 + 100*(f0 big) + 200*(f1 big) + 400*(f2 big) + 800*(f3 big) us
// ============================================================
__global__ void spin_probe(const int* __restrict__ flags,
                           float* __restrict__ sink) {
  int w = 0;
  if (flags[0] > 100000) w += 1;
  if (flags[1] > 100000) w += 2;
  if (flags[2] > 100000) w += 4;
  if (flags[3] > 1000)   w += 8;
  const int iters = 30000 + 60000 * w;
  float v = 1.0f;
  for (int i = 0; i < iters; ++i) v = __builtin_fmaf(v, 1.0000001f, 1e-7f);
  if (v == 123.456f) sink[8] = v;   // never true; keeps the chain alive
}

// ============================================================
// Known-good round-1 fp32 kernel: writes the final (validated) output.
// ============================================================
constexpr int BT = 32;
constexpr int NT = 32;
constexpr int MT = 16;
constexpr int RS = 12;
constexpr int MS = BT * RS + 4;

struct f8 { float v[8]; };

__device__ inline f8 ld8(const float* p) {
  f8 r;
  float4 a = *(const float4*)p;
  float4 b = *(const float4*)(p + 4);
  r.v[0] = a.x; r.v[1] = a.y; r.v[2] = a.z; r.v[3] = a.w;
  r.v[4] = b.x; r.v[5] = b.y; r.v[6] = b.z; r.v[7] = b.w;
  return r;
}

__global__ __launch_bounds__(256) void sgp_fused(
    const float* __restrict__ x, const float* __restrict__ wl,
    const float* __restrict__ blft, const float* __restrict__ wr,
    const float* __restrict__ an, const float* __restrict__ wgp,
    float* __restrict__ out) {
  constexpr Tables T = make_tables();
  __shared__ float xs[MT * MS];
  __shared__ float wsh[MT * MS];
  const int tid = threadIdx.x;
  const int tx = tid & 15;
  const int ty = tid >> 4;
  const int bb = blockIdx.x * BT;
  const int nn = blockIdx.y * NT;
  const int rl = tid >> 4;
  const int cm = tid & 15;
  float accL[2][2][8];
  float accR[2][2][8];
  #pragma unroll
  for (int a = 0; a < 2; ++a)
    #pragma unroll
    for (int c = 0; c < 2; ++c)
      #pragma unroll
      for (int i = 0; i < 8; ++i) { accL[a][c][i] = 0.f; accR[a][c][i] = 0.f; }
  for (int mm = 0; mm < Fsz; mm += MT) {
    {
      const float* g0 = x + (((size_t)(bb + rl)) * Fsz + (mm + cm)) * 8;
      const float* g1 = x + (((size_t)(bb + rl + 16)) * Fsz + (mm + cm)) * 8;
      float4 a0 = ((const float4*)g0)[0];
      float4 a1 = ((const float4*)g0)[1];
      float4 b0 = ((const float4*)g1)[0];
      float4 b1 = ((const float4*)g1)[1];
      *(float4*)&xs[cm * MS + rl * RS + 0] = a0;
      *(float4*)&xs[cm * MS + rl * RS + 4] = a1;
      *(float4*)&xs[cm * MS + (rl + 16) * RS + 0] = b0;
      *(float4*)&xs[cm * MS + (rl + 16) * RS + 4] = b1;
      float4 l0 = *(const float4*)(wl + (((size_t)(nn + rl)) * Fsz + (mm + cm)) * 4);
      float4 l1 = *(const float4*)(wl + (((size_t)(nn + rl + 16)) * Fsz + (mm + cm)) * 4);
      float4 r0 = *(const float4*)(wr + (((size_t)(nn + rl)) * Fsz + (mm + cm)) * 4);
      float4 r1 = *(const float4*)(wr + (((size_t)(nn + rl + 16)) * Fsz + (mm + cm)) * 4);
      *(float4*)&wsh[cm * MS + rl * RS + 0] = l0;
      *(float4*)&wsh[cm * MS + rl * RS + 4] = r0;
      *(float4*)&wsh[cm * MS + (rl + 16) * RS + 0] = l1;
      *(float4*)&wsh[cm * MS + (rl + 16) * RS + 4] = r1;
    }
    __syncthreads();
    #pragma unroll
    for (int m = 0; m < MT; ++m) {
      f8 xf0 = ld8(&xs[m * MS + ty * RS]);
      f8 xf1 = ld8(&xs[m * MS + (ty + 16) * RS]);
      f8 wv0 = ld8(&wsh[m * MS + tx * RS]);
      f8 wv1 = ld8(&wsh[m * MS + (tx + 16) * RS]);
      #pragma unroll
      for (int i = 0; i < 8; ++i) {
        const int g = T.gr[i];
        accL[0][0][i] += xf0.v[i] * wv0.v[g];
        accR[0][0][i] += xf0.v[i] * wv0.v[4 + g];
        accL[0][1][i] += xf0.v[i] * wv1.v[g];
        accR[0][1][i] += xf0.v[i] * wv1.v[4 + g];
        accL[1][0][i] += xf1.v[i] * wv0.v[g];
        accR[1][0][i] += xf1.v[i] * wv0.v[4 + g];
        accL[1][1][i] += xf1.v[i] * wv1.v[g];
        accR[1][1][i] += xf1.v[i] * wv1.v[4 + g];
      }
    }
    __syncthreads();
  }
  const float inv_sqrt2 = 0.7071067811865476f;
  #pragma unroll
  for (int c = 0; c < 2; ++c) {
    const int n = nn + tx + c * 16;
    float4 anv = *(const float4*)(an + (size_t)n * 4);
    const float bias = blft[n];
    float wd[20];
    #pragma unroll
    for (int q = 0; q < 5; ++q) {
      float4 w4 = *(const float4*)(wgp + (size_t)n * 20 + q * 4);
      wd[q * 4 + 0] = w4.x; wd[q * 4 + 1] = w4.y;
      wd[q * 4 + 2] = w4.z; wd[q * 4 + 3] = w4.w;
    }
    float sg[4];
    sg[0] = 1.f / (1.f + expf(-anv.x));
    sg[1] = 1.f / (1.f + expf(-anv.y));
    sg[2] = 1.f / (1.f + expf(-anv.z));
    sg[3] = 1.f / (1.f + expf(-anv.w));
    #pragma unroll
    for (int a = 0; a < 2; ++a) {
      const int b = bb + ty + a * 16;
      const float* r = accR[a][c];
      float q0 = r[0] * r[0];
      float q1 = r[1] * r[1] + r[2] * r[2] + r[3] * r[3];
      float q2 = r[4] * r[4] + r[5] * r[5] + r[6] * r[6];
      float q3 = r[7] * r[7];
      float nrm[4];
      nrm[0] = sqrtf(sqrtf(q0 * q0 + 1e-16f));
      nrm[1] = sqrtf(sqrtf(q1 * q1 + 1e-16f));
      nrm[2] = sqrtf(sqrtf(q2 * q2 + 1e-16f));
      nrm[3] = sqrtf(sqrtf(q3 * q3 + 1e-16f));
      float invn[4];
      #pragma unroll
      for (int g = 0; g < 4; ++g)
        invn[g] = 1.0f / (sg[g] * (nrm[g] - 1.0f) + 1.0f + 1e-6f);
      float xr[8];
      #pragma unroll
      for (int i = 0; i < 8; ++i) xr[i] = r[i] * invn[T.gr[i]];
      f8 xv = ld8(x + (((size_t)b) * Fsz + n) * 8);
      float gp[8] = {0, 0, 0, 0, 0, 0, 0, 0};
      #pragma unroll
      for (int i = 0; i < 8; ++i) {
        #pragma unroll
        for (int k = 0; k < 8; ++k) {
          const int p = i * 8 + k;
          gp[T.jidx[p]] += T.sgn[p] * wd[T.path[p]] * xv.v[i] * xr[k];
        }
      }
      float o[8];
      #pragma unroll
      for (int i = 0; i < 8; ++i)
        o[i] = (accL[a][c][i] + gp[i] + (i == 0 ? bias : 0.f)) * inv_sqrt2;
      float4* dst = (float4*)(out + (((size_t)b) * Fsz + n) * 8);
      dst[0] = make_float4(o[0], o[1], o[2], o[3]);
      dst[1] = make_float4(o[4], o[5], o[6], o[7]);
    }
  }
}

}  // namespace

extern "C" void kernel_launch(void* const* d_in, const int* in_sizes, int n_in,
                              void* d_out, int out_size, void* d_ws, size_t ws_size,
                              hipStream_t stream) {
  const float* x   = (const float*)d_in[0];
  const float* wl  = (const float*)d_in[1];
  const float* bl  = (const float*)d_in[2];
  const float* wr  = (const float*)d_in[3];
  const float* an  = (const float*)d_in[4];
  const float* wgp = (const float*)d_in[5];
  float* out = (float*)d_out;
  int*   flags = (int*)d_out;   // borrowed; overwritten by sgp_fused afterwards

  const size_t xt_bytes = (size_t)8 * Bsz * Fsz * 2;
  const size_t wb_bytes = (size_t)8 * Fsz * Fsz * 2;
  if (ws_size >= xt_bytes + wb_bytes) {
    unsigned short* xt  = (unsigned short*)d_ws;
    unsigned short* wbp = (unsigned short*)((char*)d_ws + xt_bytes);
    zflags<<<1, 64, 0, stream>>>(flags);
    xpose<<<dim3(Bsz / 32, Fsz / 64), 256, 0, stream>>>(x, xt);
    wpack<<<512, 256, 0, stream>>>(wl, wr, xt + (xt_bytes / 2));
    (void)wbp;
    xcheck<<<64, 256, 0, stream>>>(x, xt, flags);
    mfma_cmp<<<dim3(Bsz / 32, Fsz / 32), 256, 0, stream>>>(
        xt, xt + (xt_bytes / 2), x, wl, wr, flags);
    spin_probe<<<1, 64, 0, stream>>>(flags, out);
  }
  // Final authoritative output (proven round-1 kernel):
  sgp_fused<<<dim3(Bsz / BT, Fsz / NT), 256, 0, stream>>>(x, wl, bl, wr, an,
                                                          wgp, out);
}